// Round 1
// baseline (524.620 us; speedup 1.0000x reference)
//
#include <hip/hip_runtime.h>
#include <math.h>

#define BB 2
#define CC 64
#define HH 256
#define WW 256
#define KK 9
#define NOFF 10          // offset channels actually needed (0..8 used, 9 for GN stats of group 4)
#define HW (HH*WW)

// ---------------- transpose x: (B,C,H,W) -> (B,H,W,C) ----------------
__global__ __launch_bounds__(256) void transpose_x_kernel(const float* __restrict__ x,
                                                          float* __restrict__ xT) {
    __shared__ float tile[64 * 65];
    int wt = blockIdx.x & 3;
    int h  = (blockIdx.x >> 2) & 255;
    int b  = blockIdx.x >> 10;
    int w0 = wt * 64;
    int t  = threadIdx.x;
    {
        int wl = t & 63, crow = t >> 6;
        for (int it = 0; it < 16; ++it) {
            int c = crow + it * 4;
            float v = x[(((b * CC + c) * HH + h) * WW) + w0 + wl];   // coalesced along w
            tile[wl * 65 + c] = v;
        }
    }
    __syncthreads();
    {
        int c = t & 63, wrow = t >> 6;
        for (int it = 0; it < 16; ++it) {
            int wl = wrow + it * 4;
            xT[(((b * HH + h) * WW) + w0 + wl) * CC + c] = tile[wl * 65 + c]; // coalesced along c
        }
    }
}

// ---------------- transpose w_dsc (co,ci,k) -> wT2[k][ci/4][co][ci%4] ----------------
__global__ void transpose_w_kernel(const float* __restrict__ w_dsc, float* __restrict__ wT2) {
    int idx = blockIdx.x * 256 + threadIdx.x;
    if (idx < CC * CC * KK) {
        int co  = idx / (CC * KK);
        int rem = idx % (CC * KK);
        int ci  = rem / KK;
        int k   = rem % KK;
        wT2[(((k * 16) + (ci >> 2)) * 64 + co) * 4 + (ci & 3)] = w_dsc[idx];
    }
}

// ---------------- offset conv 3x3 (10 of 18 channels) ----------------
__global__ __launch_bounds__(256) void conv_off_kernel(const float* __restrict__ xT,
                                                       const float* __restrict__ w_off,
                                                       const float* __restrict__ b_off,
                                                       float* __restrict__ off_raw) {
    __shared__ float wLDS[NOFF * 64 * 9];      // 23 KB, first 5760 floats of w_off (oc-major)
    int t = threadIdx.x;
    for (int i = t; i < NOFF * 64 * 9; i += 256) wLDS[i] = w_off[i];
    __syncthreads();
    int wv = t >> 6, lane = t & 63;
    int pid = blockIdx.x * 4 + wv;            // one wave per pixel
    int b = pid >> 16;
    int h = (pid >> 8) & 255;
    int w = pid & 255;
    float acc[NOFF];
#pragma unroll
    for (int oc = 0; oc < NOFF; ++oc) acc[oc] = 0.f;
#pragma unroll
    for (int tap = 0; tap < 9; ++tap) {
        int y = h + tap / 3 - 1, xx = w + tap % 3 - 1;
        float v = 0.f;
        if (y >= 0 && y < HH && xx >= 0 && xx < WW)
            v = xT[(((b * HH + y) * WW) + xx) * CC + lane];          // coalesced over ci
#pragma unroll
        for (int oc = 0; oc < NOFF; ++oc)
            acc[oc] += v * wLDS[oc * 576 + lane * 9 + tap];
    }
#pragma unroll
    for (int oc = 0; oc < NOFF; ++oc) {
        float v = acc[oc];
        for (int m = 32; m > 0; m >>= 1) v += __shfl_xor(v, m, 64);
        if (lane == 0)
            off_raw[(b * NOFF + oc) * HW + h * WW + w] = v + b_off[oc];
    }
}

// ---------------- GN stats, stage 1 for offsets: 10 groups x 8 parts ----------------
__global__ __launch_bounds__(256) void gn_off_partial_kernel(const float* __restrict__ off_raw,
                                                             float* __restrict__ partials) {
    int comb = blockIdx.x >> 3;    // b*5+g  (0..9)
    int part = blockIdx.x & 7;
    const float* base = off_raw + (size_t)comb * 131072 + part * 16384;
    float s = 0.f, s2 = 0.f;
    for (int i = threadIdx.x; i < 16384; i += 256) {
        float v = base[i];
        s += v; s2 += v * v;
    }
    __shared__ float rs[256], rs2[256];
    rs[threadIdx.x] = s; rs2[threadIdx.x] = s2;
    __syncthreads();
    for (int o = 128; o > 0; o >>= 1) {
        if (threadIdx.x < o) { rs[threadIdx.x] += rs[threadIdx.x + o]; rs2[threadIdx.x] += rs2[threadIdx.x + o]; }
        __syncthreads();
    }
    if (threadIdx.x == 0) {
        partials[blockIdx.x * 2]     = rs[0];
        partials[blockIdx.x * 2 + 1] = rs2[0];
    }
}

// ---------------- GN stats, stage 1 for output: 32 groups x 16 parts ----------------
__global__ __launch_bounds__(256) void gn_out_partial_kernel(const float* __restrict__ tmp,
                                                             float* __restrict__ partials) {
    int comb = blockIdx.x >> 4;    // b*16+g (0..31)
    int part = blockIdx.x & 15;
    int b = comb >> 4, g = comb & 15;
    float s = 0.f, s2 = 0.f;
    for (int i = threadIdx.x; i < 16384; i += 256) {
        int idx = part * 16384 + i;
        int c = idx & 3, pix = idx >> 2;
        float v = tmp[((size_t)b * HW + pix) * CC + g * 4 + c];
        s += v; s2 += v * v;
    }
    __shared__ float rs[256], rs2[256];
    rs[threadIdx.x] = s; rs2[threadIdx.x] = s2;
    __syncthreads();
    for (int o = 128; o > 0; o >>= 1) {
        if (threadIdx.x < o) { rs[threadIdx.x] += rs[threadIdx.x + o]; rs2[threadIdx.x] += rs2[threadIdx.x + o]; }
        __syncthreads();
    }
    if (threadIdx.x == 0) {
        partials[blockIdx.x * 2]     = rs[0];
        partials[blockIdx.x * 2 + 1] = rs2[0];
    }
}

// ---------------- GN stats, stage 2 (generic) ----------------
__global__ __launch_bounds__(64) void gn_reduce_kernel(const float* __restrict__ partials,
                                                       int nparts, float inv_n,
                                                       float* __restrict__ stats) {
    int g = blockIdx.x;
    int lane = threadIdx.x;
    float s  = (lane < nparts) ? partials[(g * nparts + lane) * 2]     : 0.f;
    float s2 = (lane < nparts) ? partials[(g * nparts + lane) * 2 + 1] : 0.f;
    for (int m = 8; m > 0; m >>= 1) { s += __shfl_xor(s, m, 64); s2 += __shfl_xor(s2, m, 64); }
    if (lane == 0) {
        float mean = s * inv_n;
        float var  = s2 * inv_n - mean * mean;
        stats[g * 2]     = mean;
        stats[g * 2 + 1] = rsqrtf(var + 1e-5f);
    }
}

// ---------------- fused main kernel: GN+tanh+cumsum -> sample -> 9x1 strip conv ----------------
__global__ __launch_bounds__(256) void main_kernel(const float* __restrict__ xT,
                                                   const float* __restrict__ off_raw,
                                                   const float* __restrict__ stats_off,
                                                   const float* __restrict__ gno_w,
                                                   const float* __restrict__ gno_b,
                                                   const float* __restrict__ wT2,
                                                   const float* __restrict__ b_dsc,
                                                   float* __restrict__ tmp) {
    __shared__ float ds[16 * 9 * 64];   // 36,864 B : samples d[pix][k][ci]
    __shared__ float iyl[16 * 9];
    int t  = threadIdx.x;
    int wt = blockIdx.x & 15;
    int h  = (blockIdx.x >> 4) & 255;
    int b  = blockIdx.x >> 12;
    int w0 = wt * 16;

    // Phase A: 16 threads -> offsets, GN, tanh, outward cumsum, y-coords
    if (t < 16) {
        int w = w0 + t;
        float tk[9];
#pragma unroll
        for (int k = 0; k < 9; ++k) {
            float v = off_raw[(b * NOFF + k) * HW + h * WW + w];
            int g = k >> 1;                       // groups of 2 channels
            float m = stats_off[(b * 5 + g) * 2];
            float r = stats_off[(b * 5 + g) * 2 + 1];
            tk[k] = tanhf((v - m) * r * gno_w[k] + gno_b[k]);
        }
        float yc[9];
        float c = 0.f;
        for (int k = 3; k >= 0; --k) { c += tk[k]; yc[k] = c; }   // sum_{j=k..3}
        yc[4] = 0.f;
        c = 0.f;
        for (int k = 5; k < 9; ++k) { c += tk[k]; yc[k] = c; }    // sum_{j=5..k}
#pragma unroll
        for (int k = 0; k < 9; ++k) {
            float y = (float)h + yc[k];
            iyl[t * 9 + k] = fminf(fmaxf(y, 0.f), 255.f);
        }
    }
    __syncthreads();

    int wv = t >> 6, lane = t & 63;

    // Phase B: sample. x-coords are exact integers -> 2-tap lerp in y only.
#pragma unroll
    for (int j = 0; j < 4; ++j) {
        int pib = wv * 4 + j;
        int w = w0 + pib;
#pragma unroll
        for (int k = 0; k < 9; ++k) {
            float y   = iyl[pib * 9 + k];
            float y0f = floorf(y);
            float fy  = y - y0f;
            int y0 = (int)y0f;
            int y1 = min(y0 + 1, 255);
            int xc = min(max(w + k - 4, 0), 255);
            const float* p0 = xT + (((size_t)(b * HH + y0) * WW) + xc) * CC;
            const float* p1 = xT + (((size_t)(b * HH + y1) * WW) + xc) * CC;
            float v0 = p0[lane], v1 = p1[lane];
            ds[(pib * 9 + k) * 64 + lane] = v0 + fy * (v1 - v0);
        }
    }
    __syncthreads();

    // Phase C: strip conv. thread = (co, wave); each wave owns 4 pixels.
    int co = lane;
    float acc0 = 0.f, acc1 = 0.f, acc2 = 0.f, acc3 = 0.f;
    const float4* ds4 = (const float4*)ds;
    const float4* w4p = (const float4*)wT2;
#pragma unroll
    for (int k = 0; k < 9; ++k) {
#pragma unroll
        for (int c4 = 0; c4 < 16; ++c4) {
            float4 w4 = w4p[(k * 16 + c4) * 64 + co];            // coalesced 16B/lane
            float4 d0 = ds4[((wv * 4 + 0) * 9 + k) * 16 + c4];   // LDS broadcast
            float4 d1 = ds4[((wv * 4 + 1) * 9 + k) * 16 + c4];
            float4 d2 = ds4[((wv * 4 + 2) * 9 + k) * 16 + c4];
            float4 d3 = ds4[((wv * 4 + 3) * 9 + k) * 16 + c4];
            acc0 += w4.x * d0.x + w4.y * d0.y + w4.z * d0.z + w4.w * d0.w;
            acc1 += w4.x * d1.x + w4.y * d1.y + w4.z * d1.z + w4.w * d1.w;
            acc2 += w4.x * d2.x + w4.y * d2.y + w4.z * d2.z + w4.w * d2.w;
            acc3 += w4.x * d3.x + w4.y * d3.y + w4.z * d3.z + w4.w * d3.w;
        }
    }
    float bias = b_dsc[co];
    size_t base = ((size_t)(b * HH + h) * WW + w0 + wv * 4) * CC + co;
    tmp[base + 0 * CC] = acc0 + bias;
    tmp[base + 1 * CC] = acc1 + bias;
    tmp[base + 2 * CC] = acc2 + bias;
    tmp[base + 3 * CC] = acc3 + bias;
}

// ---------------- final: NHWC tmp -> GN -> ReLU -> NCHW out ----------------
__global__ __launch_bounds__(256) void apply_final_kernel(const float* __restrict__ tmp,
                                                          const float* __restrict__ stats,
                                                          const float* __restrict__ gn_w,
                                                          const float* __restrict__ gn_b,
                                                          float* __restrict__ out) {
    __shared__ float tile[64 * 65];
    int wt = blockIdx.x & 3;
    int h  = (blockIdx.x >> 2) & 255;
    int b  = blockIdx.x >> 10;
    int w0 = wt * 64;
    int t  = threadIdx.x;
    {
        int co = t & 63, wrow = t >> 6;
        for (int it = 0; it < 16; ++it) {
            int wl = wrow + it * 4;
            tile[co * 65 + wl] = tmp[((size_t)(b * HW) + h * WW + w0 + wl) * CC + co]; // coalesced over co
        }
    }
    __syncthreads();
    {
        int wl = t & 63, crow = t >> 6;
        for (int it = 0; it < 16; ++it) {
            int co = crow + it * 4;
            float v = tile[co * 65 + wl];
            int g = co >> 2;
            float m = stats[(b * 16 + g) * 2];
            float r = stats[(b * 16 + g) * 2 + 1];
            v = (v - m) * r * gn_w[co] + gn_b[co];
            v = fmaxf(v, 0.f);
            out[((size_t)(b * CC + co) * HH + h) * WW + w0 + wl] = v;  // coalesced over w
        }
    }
}

extern "C" void kernel_launch(void* const* d_in, const int* in_sizes, int n_in,
                              void* d_out, int out_size, void* d_ws, size_t ws_size,
                              hipStream_t stream) {
    const float* x     = (const float*)d_in[0];
    const float* w_off = (const float*)d_in[1];
    const float* b_off = (const float*)d_in[2];
    const float* gno_w = (const float*)d_in[3];
    const float* gno_b = (const float*)d_in[4];
    const float* w_dsc = (const float*)d_in[5];
    const float* b_dsc = (const float*)d_in[6];
    const float* gn_w  = (const float*)d_in[7];
    const float* gn_b  = (const float*)d_in[8];
    float* out = (float*)d_out;

    char* ws = (char*)d_ws;
    float* xT        = (float*)(ws);                 // 33,554,432 B
    float* tmp       = (float*)(ws + 33554432);      // 33,554,432 B
    float* off_raw   = (float*)(ws + 67108864);      //  5,242,880 B
    float* wT2       = (float*)(ws + 72351744);      //    147,456 B
    float* stats_off = (float*)(ws + 72499200);      //         80 B
    float* stats_out = (float*)(ws + 72499712);      //        256 B
    float* partials  = (float*)(ws + 72500224);      //      4,096 B (stage-1 sums)

    hipLaunchKernelGGL(transpose_x_kernel, dim3(2048), dim3(256), 0, stream, x, xT);
    hipLaunchKernelGGL(transpose_w_kernel, dim3(144), dim3(256), 0, stream, w_dsc, wT2);
    hipLaunchKernelGGL(conv_off_kernel, dim3(32768), dim3(256), 0, stream, xT, w_off, b_off, off_raw);
    hipLaunchKernelGGL(gn_off_partial_kernel, dim3(80), dim3(256), 0, stream, off_raw, partials);
    hipLaunchKernelGGL(gn_reduce_kernel, dim3(10), dim3(64), 0, stream, partials, 8,
                       1.0f / 131072.0f, stats_off);
    hipLaunchKernelGGL(main_kernel, dim3(8192), dim3(256), 0, stream,
                       xT, off_raw, stats_off, gno_w, gno_b, wT2, b_dsc, tmp);
    hipLaunchKernelGGL(gn_out_partial_kernel, dim3(512), dim3(256), 0, stream, tmp, partials);
    hipLaunchKernelGGL(gn_reduce_kernel, dim3(32), dim3(64), 0, stream, partials, 16,
                       1.0f / 262144.0f, stats_out);
    hipLaunchKernelGGL(apply_final_kernel, dim3(2048), dim3(256), 0, stream,
                       tmp, stats_out, gn_w, gn_b, out);
}

// Round 2
// 225.805 us; speedup vs baseline: 2.3233x; 2.3233x over previous
//
#include <hip/hip_runtime.h>
#include <math.h>

#define BB 2
#define CC 64
#define HH 256
#define WW 256
#define KK 9
#define NOFF 10          // offset channels actually needed (0..8 used, 9 for GN stats of group 4)
#define HW (HH*WW)

typedef __attribute__((ext_vector_type(8))) short s16x8;   // 8 bf16 = 4 VGPRs (MFMA A/B frag)
typedef __attribute__((ext_vector_type(4))) float f32x4;   // MFMA C/D frag

__device__ __forceinline__ unsigned short f2bf(float f) {
    unsigned u = __float_as_uint(f);
    unsigned r = u + 0x7fffu + ((u >> 16) & 1u);   // RTNE
    return (unsigned short)(r >> 16);
}

// ---------------- transpose x: (B,C,H,W) -> (B,H,W,C) ----------------
__global__ __launch_bounds__(256) void transpose_x_kernel(const float* __restrict__ x,
                                                          float* __restrict__ xT) {
    __shared__ float tile[64 * 65];
    int wt = blockIdx.x & 3;
    int h  = (blockIdx.x >> 2) & 255;
    int b  = blockIdx.x >> 10;
    int w0 = wt * 64;
    int t  = threadIdx.x;
    {
        int wl = t & 63, crow = t >> 6;
        for (int it = 0; it < 16; ++it) {
            int c = crow + it * 4;
            float v = x[(((b * CC + c) * HH + h) * WW) + w0 + wl];
            tile[wl * 65 + c] = v;
        }
    }
    __syncthreads();
    {
        int c = t & 63, wrow = t >> 6;
        for (int it = 0; it < 16; ++it) {
            int wl = wrow + it * 4;
            xT[(((b * HH + h) * WW) + w0 + wl) * CC + c] = tile[wl * 65 + c];
        }
    }
}

// ---------------- pack weights into MFMA B-fragment order (bf16) ----------------
// woffB: [kb(18)][lane(64)][j(8)]  for offset conv, n = oc (pad to 16), kk = tap*64+ci
// wdscB: [nt(4)][kb(18)][lane(64)][j(8)] for strip conv, n = nt*16+(L&15), kk = k*64+ci
__global__ __launch_bounds__(256) void pack_weights_kernel(const float* __restrict__ w_off,
                                                           const float* __restrict__ w_dsc,
                                                           unsigned short* __restrict__ woffB,
                                                           unsigned short* __restrict__ wdscB) {
    int idx = blockIdx.x * 256 + threadIdx.x;
    if (idx < 18 * 64 * 8) {
        int kb = idx >> 9;
        int L  = (idx >> 3) & 63;
        int j  = idx & 7;
        int n = L & 15, quad = L >> 4;
        int kk = kb * 32 + quad * 8 + j;
        int tap = kk >> 6, ci = kk & 63;
        float v = (n < NOFF) ? w_off[(n * 64 + ci) * 9 + tap] : 0.f;
        woffB[idx] = f2bf(v);
    }
    if (idx < 4 * 18 * 64 * 8) {
        int nt = idx / 9216;
        int r  = idx - nt * 9216;
        int kb = r >> 9;
        int L  = (r >> 3) & 63;
        int j  = r & 7;
        int n = L & 15, quad = L >> 4;
        int co = nt * 16 + n;
        int kk = kb * 32 + quad * 8 + j;
        int k = kk >> 6, ci = kk & 63;
        wdscB[idx] = f2bf(w_dsc[(co * 64 + ci) * 9 + k]);
    }
}

// ---------------- offset conv 3x3 via MFMA (direct global A-frag loads) ----------------
__global__ __launch_bounds__(256) void conv_off_mfma(const float* __restrict__ xT,
                                                     const unsigned short* __restrict__ woffB,
                                                     const float* __restrict__ b_off,
                                                     float* __restrict__ off_raw) {
    int t = threadIdx.x;
    int L = t & 63, v = t >> 6;
    int b  = blockIdx.x >> 10;
    int h  = (blockIdx.x >> 2) & 255;
    int w0 = (blockIdx.x & 3) << 6;
    int m = L & 15, quad = L >> 4;

    s16x8 breg[18];
#pragma unroll
    for (int kb = 0; kb < 18; ++kb)
        breg[kb] = *(const s16x8*)(woffB + (kb * 64 + L) * 8);

    int wpix = w0 + v * 16 + m;
    f32x4 acc = {0.f, 0.f, 0.f, 0.f};
#pragma unroll
    for (int kb = 0; kb < 18; ++kb) {
        int tap = kb >> 1;
        int dy = tap / 3 - 1, dx = tap % 3 - 1;
        int y  = h + dy;
        int xc = wpix + dx;
        int ci0 = ((kb & 1) << 5) + quad * 8;
        bool ok = ((unsigned)y < 256u) && ((unsigned)xc < 256u);
        int ya = min(max(y, 0), 255);
        int xa = min(max(xc, 0), 255);
        const float* p = xT + (((size_t)((b << 8) + ya) << 8) + xa) * 64 + ci0;
        float4 a0 = *(const float4*)p;
        float4 a1 = *(const float4*)(p + 4);
        if (!ok) { a0 = make_float4(0,0,0,0); a1 = make_float4(0,0,0,0); }
        s16x8 a;
        a[0] = (short)f2bf(a0.x); a[1] = (short)f2bf(a0.y);
        a[2] = (short)f2bf(a0.z); a[3] = (short)f2bf(a0.w);
        a[4] = (short)f2bf(a1.x); a[5] = (short)f2bf(a1.y);
        a[6] = (short)f2bf(a1.z); a[7] = (short)f2bf(a1.w);
        acc = __builtin_amdgcn_mfma_f32_16x16x32_bf16(a, breg[kb], acc, 0, 0, 0);
    }
    int oc = L & 15;   // D col
    if (oc < NOFF) {
        float bo = b_off[oc];
#pragma unroll
        for (int r = 0; r < 4; ++r) {
            int w = w0 + v * 16 + quad * 4 + r;     // D row
            off_raw[((b * NOFF + oc) << 16) + (h << 8) + w] = acc[r] + bo;
        }
    }
}

// ---------------- GN stats, stage 1 for offsets (contiguous) ----------------
__global__ __launch_bounds__(256) void gn_off_partial_kernel(const float* __restrict__ off_raw,
                                                             float* __restrict__ partials) {
    int comb = blockIdx.x >> 3;    // b*5+g  (0..9), each = 2 channels contiguous
    int part = blockIdx.x & 7;
    const float* base = off_raw + (size_t)comb * 131072 + part * 16384;
    float s = 0.f, s2 = 0.f;
    for (int i = threadIdx.x; i < 16384; i += 256) {
        float v = base[i];
        s += v; s2 += v * v;
    }
    __shared__ float rs[256], rs2[256];
    rs[threadIdx.x] = s; rs2[threadIdx.x] = s2;
    __syncthreads();
    for (int o = 128; o > 0; o >>= 1) {
        if (threadIdx.x < o) { rs[threadIdx.x] += rs[threadIdx.x + o]; rs2[threadIdx.x] += rs2[threadIdx.x + o]; }
        __syncthreads();
    }
    if (threadIdx.x == 0) {
        partials[blockIdx.x * 2]     = rs[0];
        partials[blockIdx.x * 2 + 1] = rs2[0];
    }
}

// ---------------- GN stats for output: coalesced float4 pass over NHWC tmp ----------------
__global__ __launch_bounds__(256) void gn_out_partial2(const float* __restrict__ tmp,
                                                       float* __restrict__ partials) {
    int t = threadIdx.x;
    int blk = blockIdx.x;
    int b = blk >> 8, part = blk & 255;
    const float4* base = (const float4*)tmp + ((size_t)b << 20) + part * 4096;
    float s = 0.f, s2 = 0.f;
#pragma unroll
    for (int i = 0; i < 16; ++i) {
        float4 v = base[i * 256 + t];
        s  += v.x + v.y + v.z + v.w;
        s2 += v.x * v.x + v.y * v.y + v.z * v.z + v.w * v.w;
    }
    int g = t & 15;       // float4 index mod 16 == channel group (64ch/4)
    __shared__ float ls[16][17], ls2[16][17];
    ls[g][t >> 4] = s; ls2[g][t >> 4] = s2;
    __syncthreads();
    if (t < 16) {
        float a = 0.f, a2 = 0.f;
#pragma unroll
        for (int i = 0; i < 16; ++i) { a += ls[t][i]; a2 += ls2[t][i]; }
        partials[(((b * 16 + t) << 8) + part) * 2]     = a;
        partials[(((b * 16 + t) << 8) + part) * 2 + 1] = a2;
    }
}

// ---------------- GN stats, stage 2 (generic, nparts up to thousands) ----------------
__global__ __launch_bounds__(64) void gn_reduce_kernel(const float* __restrict__ partials,
                                                       int nparts, float inv_n,
                                                       float* __restrict__ stats) {
    int g = blockIdx.x;
    int lane = threadIdx.x;
    float s = 0.f, s2 = 0.f;
    for (int i = lane; i < nparts; i += 64) {
        s  += partials[(g * nparts + i) * 2];
        s2 += partials[(g * nparts + i) * 2 + 1];
    }
    for (int m = 32; m > 0; m >>= 1) { s += __shfl_xor(s, m, 64); s2 += __shfl_xor(s2, m, 64); }
    if (lane == 0) {
        float mean = s * inv_n;
        float var  = s2 * inv_n - mean * mean;
        stats[g * 2]     = mean;
        stats[g * 2 + 1] = rsqrtf(var + 1e-5f);
    }
}

// ---------------- fused main: GN+tanh+cumsum -> lerp-sample -> MFMA strip conv ----------------
__global__ __launch_bounds__(256) void main_mfma(const float* __restrict__ xT,
                                                 const float* __restrict__ off_raw,
                                                 const float* __restrict__ stats_off,
                                                 const float* __restrict__ gno_w,
                                                 const float* __restrict__ gno_b,
                                                 const unsigned short* __restrict__ wdscB,
                                                 const float* __restrict__ b_dsc,
                                                 float* __restrict__ tmp) {
    __shared__ unsigned short aT[16 * 584];   // A-tile: 16 px rows, pitch 584 bf16 (pad 8)
    __shared__ int   offA0[576], offA1[576];  // 64 px * 9 k element offsets into xT
    __shared__ float fyA[576];

    int t = threadIdx.x;
    int L = t & 63, nt = t >> 6;
    int b  = blockIdx.x >> 10;
    int h  = (blockIdx.x >> 2) & 255;
    int w0 = (blockIdx.x & 3) << 6;

    // Phase A: 64 threads, one pixel each: GN+tanh+outward-cumsum -> sample coords
    if (t < 64) {
        int w = w0 + t;
        float tk[9];
#pragma unroll
        for (int k = 0; k < 9; ++k) {
            float vv = off_raw[((b * NOFF + k) << 16) + (h << 8) + w];
            int g = k >> 1;
            float mmean = stats_off[(b * 5 + g) * 2];
            float rstd  = stats_off[(b * 5 + g) * 2 + 1];
            tk[k] = tanhf((vv - mmean) * rstd * gno_w[k] + gno_b[k]);
        }
        float yc[9];
        float c = 0.f;
#pragma unroll
        for (int k = 3; k >= 0; --k) { c += tk[k]; yc[k] = c; }
        yc[4] = 0.f;
        c = 0.f;
#pragma unroll
        for (int k = 5; k < 9; ++k) { c += tk[k]; yc[k] = c; }
#pragma unroll
        for (int k = 0; k < 9; ++k) {
            float y = fminf(fmaxf((float)h + yc[k], 0.f), 255.f);
            float y0f = floorf(y);
            int y0 = (int)y0f;
            int y1 = min(y0 + 1, 255);
            int xc = min(max(w + k - 4, 0), 255);
            offA0[t * 9 + k] = ((b * 256 + y0) * 256 + xc) * 64;
            offA1[t * 9 + k] = ((b * 256 + y1) * 256 + xc) * 64;
            fyA[t * 9 + k]   = y - y0f;
        }
    }

    // B-fragments: 18 kb * 16B = 72 VGPRs, loaded once, reused for 4 pixel tiles
    s16x8 wreg[18];
#pragma unroll
    for (int kb = 0; kb < 18; ++kb)
        wreg[kb] = *(const s16x8*)(wdscB + ((nt * 18 + kb) * 64 + L) * 8);

    int col = L & 15, quad = L >> 4;
    float bias = b_dsc[nt * 16 + col];

    for (int tile = 0; tile < 4; ++tile) {
        __syncthreads();   // LDS safe to overwrite (also orders phase A on tile 0)
        // Staging: 16px * 9k * 16 c4-quads = 2304 quads; 9 iters of 256 threads
#pragma unroll
        for (int it = 0; it < 9; ++it) {
            int cq   = it * 256 + t;
            int pixL = cq / 144;
            int rem  = cq - pixL * 144;
            int k  = rem >> 4, c4 = rem & 15;
            int pi = (tile * 16 + pixL) * 9 + k;
            int o0 = offA0[pi] + c4 * 4;
            int o1 = offA1[pi] + c4 * 4;
            float fy = fyA[pi];
            float4 s0 = *(const float4*)(xT + o0);
            float4 s1 = *(const float4*)(xT + o1);
            float r0 = s0.x + fy * (s1.x - s0.x);
            float r1 = s0.y + fy * (s1.y - s0.y);
            float r2 = s0.z + fy * (s1.z - s0.z);
            float r3 = s0.w + fy * (s1.w - s0.w);
            unsigned lo = (unsigned)f2bf(r0) | ((unsigned)f2bf(r1) << 16);
            unsigned hi = (unsigned)f2bf(r2) | ((unsigned)f2bf(r3) << 16);
            uint2* dst = (uint2*)&aT[pixL * 584 + k * 64 + c4 * 4];
            *dst = make_uint2(lo, hi);
        }
        __syncthreads();

        f32x4 acc = {0.f, 0.f, 0.f, 0.f};
#pragma unroll
        for (int kb = 0; kb < 18; ++kb) {
            s16x8 a = *(const s16x8*)(&aT[col * 584 + kb * 32 + quad * 8]);
            acc = __builtin_amdgcn_mfma_f32_16x16x32_bf16(a, wreg[kb], acc, 0, 0, 0);
        }
        int co = nt * 16 + col;
        size_t base = ((size_t)(b << 16) + (h << 8) + (w0 + tile * 16 + quad * 4)) * 64 + co;
#pragma unroll
        for (int r = 0; r < 4; ++r)
            tmp[base + (size_t)r * 64] = acc[r] + bias;
    }
}

// ---------------- final: NHWC tmp -> GN -> ReLU -> NCHW out ----------------
__global__ __launch_bounds__(256) void apply_final_kernel(const float* __restrict__ tmp,
                                                          const float* __restrict__ stats,
                                                          const float* __restrict__ gn_w,
                                                          const float* __restrict__ gn_b,
                                                          float* __restrict__ out) {
    __shared__ float tile[64 * 65];
    int wt = blockIdx.x & 3;
    int h  = (blockIdx.x >> 2) & 255;
    int b  = blockIdx.x >> 10;
    int w0 = wt * 64;
    int t  = threadIdx.x;
    {
        int co = t & 63, wrow = t >> 6;
        for (int it = 0; it < 16; ++it) {
            int wl = wrow + it * 4;
            tile[co * 65 + wl] = tmp[((size_t)(b * HW) + h * WW + w0 + wl) * CC + co];
        }
    }
    __syncthreads();
    {
        int wl = t & 63, crow = t >> 6;
        for (int it = 0; it < 16; ++it) {
            int co = crow + it * 4;
            float v = tile[co * 65 + wl];
            int g = co >> 2;
            float m = stats[(b * 16 + g) * 2];
            float r = stats[(b * 16 + g) * 2 + 1];
            v = (v - m) * r * gn_w[co] + gn_b[co];
            v = fmaxf(v, 0.f);
            out[((size_t)(b * CC + co) * HH + h) * WW + w0 + wl] = v;
        }
    }
}

extern "C" void kernel_launch(void* const* d_in, const int* in_sizes, int n_in,
                              void* d_out, int out_size, void* d_ws, size_t ws_size,
                              hipStream_t stream) {
    const float* x     = (const float*)d_in[0];
    const float* w_off = (const float*)d_in[1];
    const float* b_off = (const float*)d_in[2];
    const float* gno_w = (const float*)d_in[3];
    const float* gno_b = (const float*)d_in[4];
    const float* w_dsc = (const float*)d_in[5];
    const float* b_dsc = (const float*)d_in[6];
    const float* gn_w  = (const float*)d_in[7];
    const float* gn_b  = (const float*)d_in[8];
    float* out = (float*)d_out;

    char* ws = (char*)d_ws;
    float* xT              = (float*)(ws);                 // 33,554,432 B
    float* tmp             = (float*)(ws + 33554432);      // 33,554,432 B
    float* off_raw         = (float*)(ws + 67108864);      //  5,242,880 B
    unsigned short* wdscB  = (unsigned short*)(ws + 72351744);  // 73,728 B
    unsigned short* woffB  = (unsigned short*)(ws + 72425472);  // 18,432 B
    float* stats_off       = (float*)(ws + 72443904);      //         80 B
    float* stats_out       = (float*)(ws + 72444416);      //        256 B
    float* partials        = (float*)(ws + 72444928);      //     65,536 B

    hipLaunchKernelGGL(transpose_x_kernel, dim3(2048), dim3(256), 0, stream, x, xT);
    hipLaunchKernelGGL(pack_weights_kernel, dim3(144), dim3(256), 0, stream,
                       w_off, w_dsc, woffB, wdscB);
    hipLaunchKernelGGL(conv_off_mfma, dim3(2048), dim3(256), 0, stream,
                       xT, woffB, b_off, off_raw);
    hipLaunchKernelGGL(gn_off_partial_kernel, dim3(80), dim3(256), 0, stream, off_raw, partials);
    hipLaunchKernelGGL(gn_reduce_kernel, dim3(10), dim3(64), 0, stream, partials, 8,
                       1.0f / 131072.0f, stats_off);
    hipLaunchKernelGGL(main_mfma, dim3(2048), dim3(256), 0, stream,
                       xT, off_raw, stats_off, gno_w, gno_b, wdscB, b_dsc, tmp);
    hipLaunchKernelGGL(gn_out_partial2, dim3(512), dim3(256), 0, stream, tmp, partials);
    hipLaunchKernelGGL(gn_reduce_kernel, dim3(32), dim3(64), 0, stream, partials, 256,
                       1.0f / 262144.0f, stats_out);
    hipLaunchKernelGGL(apply_final_kernel, dim3(2048), dim3(256), 0, stream,
                       tmp, stats_out, gn_w, gn_b, out);
}